// Round 5
// baseline (153.152 us; speedup 1.0000x reference)
//
#include <hip/hip_runtime.h>
#include <math.h>

// GCN graph-matching net. Verified reductions (R0-R5, absmax ~0):
//  - K off-diag values only used via (K != 0) -> class-match pattern; edge MLPs dead.
//  - normA @ u collapses to O(N) inclusion-exclusion; x stays rank<=7.
//  - Multiplicative sinkhorn: A = 2^(t - rowmax) once; steps u=1/(Av), v=1/(A^T u).
// R6: 4-wave kernel; 60 sinkhorn half-step barriers -> 39.2us.
// R7: wave-0 sinkhorn, A in VGPRs + live caller state -> VGPR cap + scratch -> 174us.
// R8: wave-0 sinkhorn, A streamed from LDS, load-dot interleaved -> 4 serial
//   LDS-wait sections/half-step (~1750cy) -> 50us.
// R9/R10: forcing A register-resident (plain arrays / asm pins) -> allocator
//   rematerializes or ignores; VGPR=152 both, dur unchanged. Direction abandoned.
// R11: SCHEDULE, NOT STORAGE. A-loads are address-fixed and u-independent -> off the
//   critical path if issued early. Per phase: cluster all 16 ds_read_b128 BEFORE the
//   4 dots (one ~300cy overlapped wait, not 4 serial); FULLY UNROLL the 9-iteration
//   loop so the scheduler hoists next-phase loads above the current bpermute wait.
//   Critical path/half-step becomes dots -> sel/rcp -> bpermute (~250-300cy).
//   Exchange stays bpermute (R10-verified bit-exact).

#define SK_SCALE 28.853900817779268f   // (1/TAU = 20) * log2(e)

template<int CTRL>
__device__ __forceinline__ float dppf(float x) {
    int xi = __float_as_int(x);
    int rr = __builtin_amdgcn_update_dpp(xi, xi, CTRL, 0xF, 0xF, false);
    return __int_as_float(rr);
}
__device__ __forceinline__ float quad_sum(float v) {   // sum over lane&3 quad
    v += dppf<0xB1>(v); v += dppf<0x4E>(v); return v;
}
__device__ __forceinline__ float quad_max(float v) {
    v = fmaxf(v, dppf<0xB1>(v)); v = fmaxf(v, dppf<0x4E>(v)); return v;
}
__device__ __forceinline__ float e2f(float x) { return __builtin_amdgcn_exp2f(x); }
__device__ __forceinline__ float rcpf(float x) { return __builtin_amdgcn_rcpf(x); }
__device__ __forceinline__ float dot4(const float4 a, const float4 b) {
    return a.x*b.x + a.y*b.y + a.z*b.z + a.w*b.w;
}
__device__ __forceinline__ void fma4(float4& a, float b, const float4 c) {
    a.x += b*c.x; a.y += b*c.y; a.z += b*c.z; a.w += b*c.w;
}
__device__ __forceinline__ void add4(float4& a, const float4 c) {
    a.x += c.x; a.y += c.y; a.z += c.z; a.w += c.w;
}
__device__ __forceinline__ void ld16(const float* p, float* o) {
    #pragma unroll
    for (int t = 0; t < 4; ++t) {
        float4 v = *(const float4*)(p + 4*t);
        o[4*t+0]=v.x; o[4*t+1]=v.y; o[4*t+2]=v.z; o[4*t+3]=v.w;
    }
}
// transpose read of a 64x64 stride-64 natural array: o[m] = X[16q+m][r]
__device__ __forceinline__ void ldT(const float* X, int r, int q, float* o) {
    #pragma unroll
    for (int m = 0; m < 16; ++m) o[m] = X[(16*q + m)*64 + r];
}
__device__ __forceinline__ float dotsum16(const float* a, const float* b) {
    float s0=0,s1=0,s2=0,s3=0;
    #pragma unroll
    for (int t = 0; t < 4; ++t) {
        s0 += a[4*t+0]*b[4*t+0]; s1 += a[4*t+1]*b[4*t+1];
        s2 += a[4*t+2]*b[4*t+2]; s3 += a[4*t+3]*b[4*t+3];
    }
    return (s0+s1)+(s2+s3);
}
__device__ __forceinline__ float sum16(const float* a) {
    float s0=0,s1=0,s2=0,s3=0;
    #pragma unroll
    for (int t = 0; t < 4; ++t) {
        s0 += a[4*t+0]; s1 += a[4*t+1]; s2 += a[4*t+2]; s3 += a[4*t+3];
    }
    return (s0+s1)+(s2+s3);
}
__device__ __forceinline__ void stage16(float* dst, const float* v, float sc) {
    #pragma unroll
    for (int t = 0; t < 4; ++t)
        *(float4*)(dst + 4*t) = make_float4(v[4*t+0]*sc, v[4*t+1]*sc,
                                            v[4*t+2]*sc, v[4*t+3]*sc);
}
// Static-index quad select: returns v[q] without runtime register indexing (rule #20).
__device__ __forceinline__ float sel4(const float* v, int q) {
    float w = v[0];
    w = (q == 1) ? v[1] : w;
    w = (q == 2) ? v[2] : w;
    w = (q == 3) ? v[3] : w;
    return w;
}
// uq[m] = value of (wu in lane 4m+q); byte address q4 + 16*m. Single DS traversal.
__device__ __forceinline__ void bperm16(int q4, float w, float* o) {
    #pragma unroll
    for (int m = 0; m < 16; ++m)
        o[m] = __int_as_float(__builtin_amdgcn_ds_bpermute(q4 + 16*m, __float_as_int(w)));
}
// One matvec phase: LOAD ALL 16 b128 of A-slots FIRST (overlapped latency), THEN the
// 4 dots. A addresses are loop-invariant -> scheduler may hoist loads across phases.
__device__ __forceinline__ void dots4(const float* A, int rr, int q, const float* x,
                                      float* out4) {
    float a[4][16];
    #pragma unroll
    for (int s = 0; s < 4; ++s) ld16(A + (16*s + rr)*68 + 16*q, a[s]);
    #pragma unroll
    for (int s = 0; s < 4; ++s) out4[s] = quad_sum(dotsum16(a[s], x));
}

// 256-wide sinkhorn preamble. Thread (r,q) holds t row r cols 16q..16q+15 (tq) and
// t^T row r elems 16q..16q+15 (tt). Computes rm[r] (quad_max = full row max), writes
// exp'd A into AN, exp'd A^T into AT (per-element rmq for the transpose), and it0's
// u = 1/rowsum into up. Two barriers. Bit-identical math to the R6 reference path.
__device__ __forceinline__ void sk_pre(const float* tq, const float* tt, int r, int q,
                                       float* AN, float* AT, float* up, float* rmp) {
    float m0 = tq[0];
    #pragma unroll
    for (int j = 1; j < 16; ++j) m0 = fmaxf(m0, tq[j]);
    float rm = quad_max(m0);
    float a[16];
    #pragma unroll
    for (int j = 0; j < 16; ++j) a[j] = e2f(tq[j] - rm);
    stage16(AN + r*68 + 16*q, a, 1.0f);
    float u = rcpf(quad_sum(sum16(a)));            // it0 (row, v = 1)
    if (q == 0) { rmp[r] = rm; up[r] = u; }
    __syncthreads();                               // rmp visible to all waves
    float rmq[16]; ld16(rmp + 16*q, rmq);
    float at[16];
    #pragma unroll
    for (int j = 0; j < 16; ++j) at[j] = e2f(tt[j] - rmq[j]);
    stage16(AT + r*68 + 16*q, at, 1.0f);
    __syncthreads();                               // AN/AT/up visible to wave 0
}

// Wave-0-only sinkhorn iterations (its 1..19), ZERO barriers. A streams from LDS but
// each phase's 16 ds_read_b128 are CLUSTERED before the dots, and the 9-iteration
// loop is FULLY UNROLLED so next-phase loads hide under the exchange wait. Lane
// l: rr=l>>2, q=l&3 handles 4 row-slots (rows 16s+rr) and 4 col-slots. u/v exchange:
// value for row 16q+m lives in lane 4m+q -> 16 ds_bpermute (bit-exact move).
// Publishes it18 u / it19 v to up/vp for recon; if outp, stores out = A*u*v.
__device__ __forceinline__ void sk_iter(const float* AN, const float* AT,
                                        float* up, float* vp, int lane,
                                        float* outp) {
    const int rr = lane >> 2, q = lane & 3;
    const int q4 = q << 2;
    float uq[16]; ld16(up + 16*q, uq);             // it0 u from sk_pre
    float us[4], vs[4];
    float wu = 0.0f, wvv = 0.0f;
    #pragma unroll
    for (int p = 0; p < 9; ++p) {                  // its 1..18: 9 x (col, row)
        dots4(AT, rr, q, uq, vs);
        wvv = rcpf(sel4(vs, q));                   // v for col 16q+rr
        float vq[16]; bperm16(q4, wvv, vq);
        dots4(AN, rr, q, vq, us);
        wu = rcpf(sel4(us, q));                    // u for row 16q+rr
        bperm16(q4, wu, uq);
    }
    {   // it19 (col)
        dots4(AT, rr, q, uq, vs);
        wvv = rcpf(sel4(vs, q));
    }
    up[16*q + rr] = wu;                            // it18 u  (for recon)
    vp[16*q + rr] = wvv;                           // it19 v  (for recon)
    if (outp) {
        float vq[16]; bperm16(q4, wvv, vq);
        #pragma unroll
        for (int s = 0; s < 4; ++s) {
            float uR = rcpf(us[s]);                // us[] = it18 raw row sums
            float a[16]; ld16(AN + (16*s + rr)*68 + 16*q, a);
            #pragma unroll
            for (int t = 0; t < 4; ++t) {
                float4 o4;
                o4.x = a[4*t+0] * uR * vq[4*t+0];
                o4.y = a[4*t+1] * uR * vq[4*t+1];
                o4.z = a[4*t+2] * uR * vq[4*t+2];
                o4.w = a[4*t+3] * uR * vq[4*t+3];
                *(float4*)(outp + (16*s + rr)*64 + 16*q + 4*t) = o4;
            }
        }
    }
}

// Post-sinkhorn reconstruction for all 256 threads: s = A * u * v, both orientations.
// A read back from LDS (exact fp32 round trip of the exp'd values).
__device__ __forceinline__ void sk_recon(const float* AN, const float* AT, int r, int q,
                                         const float* up, const float* vp,
                                         float* sv, float* st) {
    float ur = up[r], vr = vp[r];
    float uq[16], vq[16], an[16], at[16];
    ld16(up + 16*q, uq); ld16(vp + 16*q, vq);
    ld16(AN + r*68 + 16*q, an); ld16(AT + r*68 + 16*q, at);
    #pragma unroll
    for (int m = 0; m < 16; ++m) {
        sv[m] = an[m] * ur * vq[m];
        st[m] = at[m] * uq[m] * vr;
    }
}

// normA matvec, dual vectors x dual orientations, ONE barrier. u2==nullptr -> ones.
__device__ __forceinline__ void matvec_dual(const float* u1, const float* u1t,
                                            const float* u2, const float* u2t,
                                            const float* mmq, const float* dqv,
                                            const float* mmt, const float* dqt,
                                            float* o1, float* o1t, float* o2, float* o2t,
                                            int q, int r,
                                            float* WR1, float* WC1, float* WR2, float* WC2) {
    float rs1=0, rs2=0, cs1=0, cs2=0;
    #pragma unroll
    for (int m = 0; m < 16; ++m) {
        float md = mmq[m]*dqv[m], mdt = mmt[m]*dqt[m];
        rs1 += md * u1[m];               cs1 += mdt * u1t[m];
        rs2 += md * (u2 ? u2[m] : 1.0f); cs2 += mdt * (u2t ? u2t[m] : 1.0f);
    }
    rs1 = quad_sum(rs1); rs2 = quad_sum(rs2);
    cs1 = quad_sum(cs1); cs2 = quad_sum(cs2);
    if (q == 0) { WR1[r]=rs1; WR2[r]=rs2; WC1[r]=cs1; WC2[r]=cs2; }
    __syncthreads();
    float wr1[16], wc1[16], wr2[16], wc2[16];
    ld16(WR1 + 16*q, wr1); ld16(WC1 + 16*q, wc1);
    ld16(WR2 + 16*q, wr2); ld16(WC2 + 16*q, wc2);
    float W1 = quad_sum(sum16(wc1));
    float W2 = quad_sum(sum16(wc2));
    #pragma unroll
    for (int m = 0; m < 16; ++m) {
        float d = dqv[m], mm = mmq[m];
        float u1m = u1[m], u2m = u2 ? u2[m] : 1.0f;
        float z1 = mm*d*u1m, z2 = mm*d*u2m;
        o1[m] = d*((1.0f+mm)*d*u1m + mm*(W1 - rs1 - wc1[m] + z1));
        o2[m] = d*((1.0f+mm)*d*u2m + mm*(W2 - rs2 - wc2[m] + z2));
        float dt = dqt[m], mt = mmt[m];
        float u1tm = u1t[m], u2tm = u2t ? u2t[m] : 1.0f;
        float z1t = mt*dt*u1tm, z2t = mt*dt*u2tm;
        o1t[m] = dt*((1.0f+mt)*dt*u1tm + mt*(W1 - wr1[m] - cs1 + z1t));
        o2t[m] = dt*((1.0f+mt)*dt*u2tm + mt*(W2 - wr2[m] - cs2 + z2t));
    }
}

extern "C" __global__ __launch_bounds__(256, 1)
void gcn_match_kernel(const float* ego, const float* cav,
                      const float* nw1, const float* nb1, const float* nw2, const float* nb2,
                      const float* sw0, const float* sb0, const float* cw0, const float* cb0,
                      const float* kw0, const float* kb0,
                      const float* sw1, const float* sb1, const float* cw1, const float* cb1,
                      const float* kw1, const float* kb1,
                      const float* fcw, const float* fcb,
                      float* out) {
    __shared__ __align__(16) float sh_hT1[64 * 68];   // ego h^T | dots | exp'd A (nat)
    __shared__ __align__(16) float sh_hT2[64 * 68];   // cav h^T | dots^T | exp'd A^T
    // Union scratch: setup uses [w2:2048 | f1:2304 | f2:2304]; after P2 those die and
    // the same space holds the caller-state spill [T1B:4096 | SB:4096 | V0:4096].
    __shared__ __align__(16) float sh_scr[12288];
    float* const SH_W2  = sh_scr;
    float* const SH_F1  = sh_scr + 2048;
    float* const SH_F2  = sh_scr + 4352;
    float* const SH_T1B = sh_scr;          // t1 base, natural (64x64, stride 64)
    float* const SH_SB  = sh_scr + 4096;   // sacc base, natural
    float* const SH_V0  = sh_scr + 8192;   // v0 natural; later sacc natural
    __shared__ __align__(16) float sh_nw1[320];
    __shared__ __align__(16) float sh_nb1[64], sh_nb2[32];
    __shared__ __align__(16) float sh_cls1[64], sh_cf1[64], sh_cls2[64], sh_cf2[64];
    __shared__ __align__(16) float sh_n1[64], sh_n2[64], sh_Dr[64], sh_Dc[64];
    __shared__ __align__(16) float sh_up[64], sh_vp[64], sh_rmp[64];
    __shared__ __align__(16) float sh_WR1[64], sh_WC1[64], sh_WR2[64], sh_WC2[64];
    __shared__ __align__(16) float sh_sw0[16], sh_sb0[16], sh_cw0[16], sh_cb0[16];
    __shared__ __align__(16) float sh_sb1[16], sh_cb1[16];
    __shared__ __align__(16) float sh_sw1[256], sh_cw1[256];
    __shared__ __align__(16) float sh_kw0[16], sh_kw1[16], sh_fcw[16];
    __shared__ float sh_kb[4];        // kb0, kb1, fcb
    __shared__ float sh_avec[7 * 16];
    __shared__ float sh_coef[18];

    const int tid = threadIdx.x;
    const int wv = tid >> 6, lane = tid & 63;
    const int r = tid >> 2, q = tid & 3;

    // ================= P0a: stage everything (one parallel load round) ==========
    ((float4*)SH_W2)[tid]       = ((const float4*)nw2)[tid];
    ((float4*)SH_W2)[tid + 256] = ((const float4*)nw2)[tid + 256];
    if (tid < 80)       ((float4*)sh_nw1)[tid]      = ((const float4*)nw1)[tid];
    else if (tid < 96)  ((float4*)sh_nb1)[tid-80]   = ((const float4*)nb1)[tid-80];
    else if (tid < 104) ((float4*)sh_nb2)[tid-96]   = ((const float4*)nb2)[tid-96];
    else if (tid < 108) ((float4*)sh_sw0)[tid-104]  = ((const float4*)sw0)[tid-104];
    else if (tid < 112) ((float4*)sh_sb0)[tid-108]  = ((const float4*)sb0)[tid-108];
    else if (tid < 116) ((float4*)sh_cw0)[tid-112]  = ((const float4*)cw0)[tid-112];
    else if (tid < 120) ((float4*)sh_cb0)[tid-116]  = ((const float4*)cb0)[tid-116];
    else if (tid < 124) ((float4*)sh_sb1)[tid-120]  = ((const float4*)sb1)[tid-120];
    else if (tid < 128) ((float4*)sh_cb1)[tid-124]  = ((const float4*)cb1)[tid-124];
    else if (tid < 192) ((float4*)sh_sw1)[tid-128]  = ((const float4*)sw1)[tid-128];
    else                ((float4*)sh_cw1)[tid-192]  = ((const float4*)cw1)[tid-192];
    if (tid < 4)        ((float4*)sh_kw0)[tid]      = ((const float4*)kw0)[tid];
    else if (tid < 8)   ((float4*)sh_kw1)[tid-4]    = ((const float4*)kw1)[tid-4];
    else if (tid < 12)  ((float4*)sh_fcw)[tid-8]    = ((const float4*)fcw)[tid-8];
    else if (tid == 12) sh_kb[0] = kb0[0];
    else if (tid == 13) sh_kb[1] = kb1[0];
    else if (tid == 14) sh_kb[2] = fcb[0];
    if (tid < 64) { sh_cls1[tid] = ego[tid*8+6]; sh_cf1[tid] = ego[tid*8+7]; }
    else if (tid < 128) { int j = tid-64; sh_cls2[j] = cav[j*8+6]; sh_cf2[j] = cav[j*8+7]; }
    __syncthreads();

    // ================= P0b: hidden MLP (transposed store), 4 waves ==============
    {
        float4 ea = ((const float4*)ego)[lane*2], eb = ((const float4*)ego)[lane*2+1];
        float4 ca = ((const float4*)cav)[lane*2], cb = ((const float4*)cav)[lane*2+1];
        #pragma unroll
        for (int kk = 0; kk < 16; ++kk) {
            int k = 16*wv + kk;
            float b1 = sh_nb1[k];
            float w0 = sh_nw1[k],       w1 = sh_nw1[64+k],  w2_ = sh_nw1[128+k];
            float w3 = sh_nw1[192+k],   w4 = sh_nw1[256+k];
            sh_hT1[k*68 + lane] = fmaxf(b1 + ea.y*w0 + ea.z*w1 + ea.w*w2_ + eb.x*w3 + eb.y*w4, 0.0f);
            sh_hT2[k*68 + lane] = fmaxf(b1 + ca.y*w0 + ca.z*w1 + ca.w*w2_ + cb.x*w3 + cb.y*w4, 0.0f);
        }
    }
    __syncthreads();

    // ================= P1: GEMMs (waves 0,1) + avec/coef (wave 2) ===============
    if (wv < 2) {
        const float* HT = (wv == 0) ? sh_hT1 : sh_hT2;
        float* F  = (wv == 0) ? SH_F1 : SH_F2;
        float* NN = (wv == 0) ? sh_n1 : sh_n2;
        const int rr = lane >> 2, oq = lane & 3;
        float4 accA[4], accB[4];
        #pragma unroll
        for (int m = 0; m < 4; ++m) { accA[m] = make_float4(0,0,0,0); accB[m] = accA[m]; }
        #pragma unroll 4
        for (int k = 0; k < 64; ++k) {
            float4 hq = *(const float4*)(HT + k*68 + 4*rr);
            float4 wA = *(const float4*)(SH_W2 + k*32 + 4*oq);
            float4 wB = *(const float4*)(SH_W2 + k*32 + 16 + 4*oq);
            fma4(accA[0], hq.x, wA); fma4(accB[0], hq.x, wB);
            fma4(accA[1], hq.y, wA); fma4(accB[1], hq.y, wB);
            fma4(accA[2], hq.z, wA); fma4(accB[2], hq.z, wB);
            fma4(accA[3], hq.w, wA); fma4(accB[3], hq.w, wB);
        }
        float4 b2a = *(const float4*)(sh_nb2 + 4*oq);
        float4 b2b = *(const float4*)(sh_nb2 + 16 + 4*oq);
        float sq[4];
        #pragma unroll
        for (int m = 0; m < 4; ++m) {
            add4(accA[m], b2a); add4(accB[m], b2b);
            int row = 4*rr + m;
            *(float4*)(F + row*36 + 4*oq)      = accA[m];
            *(float4*)(F + row*36 + 16 + 4*oq) = accB[m];
            float q2 = dot4(accA[m], accA[m]) + dot4(accB[m], accB[m]);
            q2 += dppf<0xB1>(q2); q2 += dppf<0x4E>(q2);
            sq[m] = q2;
        }
        if (oq == 0) {
            #pragma unroll
            for (int m = 0; m < 4; ++m)
                NN[4*rr + m] = fmaxf(sqrtf(sq[m]), 1e-8f);
        }
    } else if (wv == 2) {
        if (lane < 16) {   // avec from LDS-staged weights
            int o = lane;
            float ax=0, av=0, as_=0, aw=0, au=0, ae=0, a1=0;
            #pragma unroll
            for (int k = 0; k < 16; ++k) {
                float s0k = sh_sw0[k], c0k = sh_cw0[k], b0k = sh_sb0[k] + sh_cb0[k];
                float s1ko = sh_sw1[k*16+o], c1ko = sh_cw1[k*16+o];
                ax += s0k*s1ko;  av += c0k*s1ko + s0k*c1ko;  as_ += s1ko;
                aw += c0k*c1ko;  au += c1ko;  ae += b0k*c1ko;  a1 += b0k*s1ko;
            }
            a1 += sh_sb1[o] + sh_cb1[o];
            sh_avec[0*16+o]=ax; sh_avec[1*16+o]=av; sh_avec[2*16+o]=as_;
            sh_avec[3*16+o]=aw; sh_avec[4*16+o]=au; sh_avec[5*16+o]=ae;
            sh_avec[6*16+o]=a1;
        }
        if (lane < 18) {   // coef (same wave: avec writes visible via lgkmcnt)
            int t = lane; float c = 0.0f;
            if (t == 0)      { for (int k = 0; k < 16; ++k) c += sh_sw0[k]*sh_kw0[k]; }
            else if (t == 1) { for (int k = 0; k < 16; ++k) c += sh_cw0[k]*sh_kw0[k]; }
            else if (t == 2) { for (int k = 0; k < 16; ++k) c += (sh_sb0[k]+sh_cb0[k])*sh_kw0[k]; c += sh_kb[0]; }
            else if (t < 10) { int v = t-3;
                for (int o = 0; o < 16; ++o) c += sh_avec[v*16+o]*sh_kw1[o];
                if (v == 6) c += sh_kb[1];
            } else if (t < 17) { int v = t-10;
                for (int o = 0; o < 16; ++o) c += sh_avec[v*16+o]*sh_fcw[o];
                if (v == 6) c += sh_kb[2];
            } else { for (int o = 0; o < 16; ++o) c += sh_fcw[o]; }
            sh_coef[t] = c;
        }
    }
    __syncthreads();

    // ================= P2: dots (all 4 waves, natural + transposed) + mm/degrees =
    {
        const int sc = lane & 15, rc = lane >> 4;
        float dt[4][4];
        #pragma unroll
        for (int m = 0; m < 4; ++m)
            #pragma unroll
            for (int k = 0; k < 4; ++k) dt[m][k] = 0.0f;
        for (int kq = 0; kq < 8; ++kq) {
            float4 f2q[4];
            #pragma unroll
            for (int k = 0; k < 4; ++k)
                f2q[k] = *(const float4*)(SH_F2 + (sc + 16*k)*36 + 4*kq);
            #pragma unroll
            for (int m = 0; m < 4; ++m) {
                int rrow = 16*m + 4*wv + rc;
                float4 f1q = *(const float4*)(SH_F1 + rrow*36 + 4*kq);
                #pragma unroll
                for (int k = 0; k < 4; ++k) dt[m][k] += dot4(f1q, f2q[k]);
            }
        }
        #pragma unroll
        for (int m = 0; m < 4; ++m) {
            int rrow = 16*m + 4*wv + rc;
            #pragma unroll
            for (int k = 0; k < 4; ++k) {
                sh_hT1[rrow*68 + sc + 16*k] = dt[m][k];       // dots natural
                sh_hT2[(sc + 16*k)*68 + rrow] = dt[m][k];     // dots transposed
            }
        }
    }
    float mmq[16], mmt[16], cfq[16], cft[16];
    float Drr, Dcr;
    {
        float c2q[16], c1q[16], f2v[16], f1v[16];
        ld16(sh_cls2 + 16*q, c2q); ld16(sh_cls1 + 16*q, c1q);
        ld16(sh_cf2 + 16*q, f2v);  ld16(sh_cf1 + 16*q, f1v);
        const float cls1r = sh_cls1[r], cls2r = sh_cls2[r];
        const float cf1r = sh_cf1[r],  cf2r  = sh_cf2[r];
        float dr = 0, dc = 0;
        #pragma unroll
        for (int m = 0; m < 16; ++m) {
            mmq[m] = (cls1r == c2q[m]) ? 1.0f : 0.0f;
            mmt[m] = (c1q[m] == cls2r) ? 1.0f : 0.0f;
            dr += mmq[m]; dc += mmt[m];
            cfq[m] = sqrtf(cf1r * f2v[m]);
            cft[m] = sqrtf(f1v[m] * cf2r);
        }
        Drr = quad_sum(dr);
        Dcr = quad_sum(dc);
        if (q == 0) { sh_Dr[r] = Drr; sh_Dc[r] = Dcr; }
    }
    __syncthreads();

    // ================= P3: dinv + x0, both orientations ==========================
    float dqv[16], dqt[16], x0[16], x0t[16];
    {
        float dcq[16], drq[16], n2q[16], n1q[16], dotq[16], dotTq[16];
        ld16(sh_Dc + 16*q, dcq); ld16(sh_Dr + 16*q, drq);
        ld16(sh_n2 + 16*q, n2q); ld16(sh_n1 + 16*q, n1q);
        ld16(sh_hT1 + r*68 + 16*q, dotq);
        ld16(sh_hT2 + r*68 + 16*q, dotTq);
        float Tdeg = quad_sum(sum16(dcq));
        const float n1r = sh_n1[r], n2r = sh_n2[r];
        #pragma unroll
        for (int m = 0; m < 16; ++m) {
            dqv[m] = (mmq[m] != 0.0f) ? (1.0f / sqrtf(Tdeg - Drr - dcq[m] + 3.0f)) : 1.0f;
            dqt[m] = (mmt[m] != 0.0f) ? (1.0f / sqrtf(Tdeg - drq[m] - Dcr + 3.0f)) : 1.0f;
            x0[m]  = mmq[m] * cfq[m] * (dotq[m]  / (n1r * n2q[m]));
            x0t[m] = mmt[m] * cft[m] * (dotTq[m] / (n1q[m] * n2r));
        }
    }

    // ================= matvec A: v0 = normA x0, oe = normA 1 =====================
    // (internal barrier also orders P3's hT reads before sk0's A writes)
    float v0[16], v0t[16], oe[16], oet[16];
    matvec_dual(x0, x0t, nullptr, nullptr, mmq, dqv, mmt, dqt,
                v0, v0t, oe, oet, q, r, sh_WR1, sh_WC1, sh_WR2, sh_WC2);

    // ================= t0 (both) + NATURAL t1/sacc bases; spill state ============
    // Transposed bases are NOT computed: by nat/transposed duality (bit-exact, the
    // property sk2 has always relied on) they are re-read from the natural spill.
    float t0q[16], t0t[16];
    {
        float c0 = sh_coef[0], c1 = sh_coef[1], c2 = sh_coef[2];
        float ctx = sh_coef[3], ctv = sh_coef[4];
        float ce_ = sh_coef[8], ct1 = sh_coef[9];
        float csx = sh_coef[10], csv = sh_coef[11];
        float ce2 = sh_coef[15], cs1 = sh_coef[16];
        float t1b[16], sbse[16];
        #pragma unroll
        for (int m = 0; m < 16; ++m) {
            t0q[m] = (c0*x0[m]  + c1*v0[m]  + c2) * SK_SCALE;
            t0t[m] = (c0*x0t[m] + c1*v0t[m] + c2) * SK_SCALE;
            t1b[m]  = ctx*x0[m]  + ctv*v0[m]  + ct1 + ce_*oe[m];
            sbse[m] = csx*x0[m]  + csv*v0[m]  + cs1 + ce2*oe[m];
        }
        stage16(SH_T1B + r*64 + 16*q, t1b, 1.0f);   // spill (f1/f2/w2 dead post-P2)
        stage16(SH_SB  + r*64 + 16*q, sbse, 1.0f);
        stage16(SH_V0  + r*64 + 16*q, v0, 1.0f);
    }
    // From here, NO per-thread register state survives across sinkhorn calls:
    // mm/dq recomputed, bases re-read from spill.

    // ================= sinkhorn0: 256-wide pre + wave-0 iterations ===============
    sk_pre(t0q, t0t, r, q, sh_hT1, sh_hT2, sh_up, sh_rmp);
    if (wv == 0) sk_iter(sh_hT1, sh_hT2, sh_up, sh_vp, lane, nullptr);
    __syncthreads();
    float s0v[16], s0t[16];
    sk_recon(sh_hT1, sh_hT2, r, q, sh_up, sh_vp, s0v, s0t);

    // ---- recompute mm/dq (bit-identical: same formulas, same LDS inputs) --------
    {
        float c2q[16], c1q[16];
        ld16(sh_cls2 + 16*q, c2q); ld16(sh_cls1 + 16*q, c1q);
        const float cls1r = sh_cls1[r], cls2r = sh_cls2[r];
        #pragma unroll
        for (int m = 0; m < 16; ++m) {
            mmq[m] = (cls1r == c2q[m]) ? 1.0f : 0.0f;
            mmt[m] = (c1q[m] == cls2r) ? 1.0f : 0.0f;
        }
        float dcq[16], drq[16];
        ld16(sh_Dc + 16*q, dcq); ld16(sh_Dr + 16*q, drq);
        float Tdeg = quad_sum(sum16(dcq));
        const float Dr2 = sh_Dr[r], Dc2 = sh_Dc[r];   // == P3's quad_sum values
        #pragma unroll
        for (int m = 0; m < 16; ++m) {
            dqv[m] = (mmq[m] != 0.0f) ? (1.0f / sqrtf(Tdeg - Dr2 - dcq[m] + 3.0f)) : 1.0f;
            dqt[m] = (mmt[m] != 0.0f) ? (1.0f / sqrtf(Tdeg - drq[m] - Dc2 + 3.0f)) : 1.0f;
        }
    }
    // ---- reload v0 (natural + transpose-read) -----------------------------------
    {
        float v0n[16], v0tn[16];
        ld16(SH_V0 + r*64 + 16*q, v0n);
        ldT(SH_V0, r, q, v0tn);
        #pragma unroll
        for (int m = 0; m < 16; ++m) { v0[m] = v0n[m]; v0t[m] = v0tn[m]; }
    }

    // ================= matvec B (v0, s0) -> t1, sacc =============================
    // (internal barrier orders recon/V0 reads before the sacc spill + sk1 writes)
    float ov[16], ovt[16], os[16], ost[16];
    matvec_dual(v0, v0t, s0v, s0t, mmq, dqv, mmt, dqt,
                ov, ovt, os, ost, q, r, sh_WR1, sh_WC1, sh_WR2, sh_WC2);
    float t1q[16], t1t[16];
    {
        float cts = sh_coef[5], cw_ = sh_coef[6], cu_ = sh_coef[7];
        float css = sh_coef[12], cw2 = sh_coef[13], cu2 = sh_coef[14];
        float t1b_[16], t1bt_[16], sbse_[16], sacc[16];
        ld16(SH_T1B + r*64 + 16*q, t1b_);
        ldT(SH_T1B, r, q, t1bt_);
        ld16(SH_SB + r*64 + 16*q, sbse_);
        #pragma unroll
        for (int m = 0; m < 16; ++m) {
            t1q[m] = (t1b_[m]  + cts*s0v[m] + cw_*ov[m]  + cu_*os[m])  * SK_SCALE;
            t1t[m] = (t1bt_[m] + cts*s0t[m] + cw_*ovt[m] + cu_*ost[m]) * SK_SCALE;
            sacc[m] = sbse_[m] + css*s0v[m] + cw2*ov[m]  + cu2*os[m];
        }
        // spill sacc (natural) into V0's slot: v0 consumed; V0 reads were all before
        // matvec B's internal barrier -> no race.
        stage16(SH_V0 + r*64 + 16*q, sacc, 1.0f);
    }

    // ================= sinkhorn1 ================================================
    sk_pre(t1q, t1t, r, q, sh_hT1, sh_hT2, sh_up, sh_rmp);
    if (wv == 0) sk_iter(sh_hT1, sh_hT2, sh_up, sh_vp, lane, nullptr);
    __syncthreads();
    float t2q[16], t2t[16];
    {
        float c17 = sh_coef[17];
        float s1v[16], s1t[16];
        sk_recon(sh_hT1, sh_hT2, r, q, sh_up, sh_vp, s1v, s1t);
        float saccN[16], saccT[16];
        ld16(SH_V0 + r*64 + 16*q, saccN);
        ldT(SH_V0, r, q, saccT);
        #pragma unroll
        for (int m = 0; m < 16; ++m) {
            // sacct[m] (+= c17*s1t) feeds sk2's NATURAL input; sacc feeds transposed.
            t2q[m] = (saccT[m] + c17 * s1t[m]) * SK_SCALE;
            t2t[m] = (saccN[m] + c17 * s1v[m]) * SK_SCALE;
        }
    }
    __syncthreads();   // order recon/up/vp/A1 reads before sk2's overwrites

    // ================= sinkhorn2 (wave-0) -> direct output =======================
    sk_pre(t2q, t2t, r, q, sh_hT1, sh_hT2, sh_up, sh_rmp);
    if (wv == 0) sk_iter(sh_hT1, sh_hT2, sh_up, sh_vp, lane, out);
    // waves 1-3 exit; wave 0 stores out directly (no further barriers).
}

extern "C" void kernel_launch(void* const* d_in, const int* in_sizes, int n_in,
                              void* d_out, int out_size, void* d_ws, size_t ws_size,
                              hipStream_t stream) {
    const float* ego = (const float*)d_in[0];
    const float* cav = (const float*)d_in[1];
    const float* nw1 = (const float*)d_in[2];
    const float* nb1 = (const float*)d_in[3];
    const float* nw2 = (const float*)d_in[4];
    const float* nb2 = (const float*)d_in[5];
    // d_in[6..9] = edge MLP weights: dead code (edge values only feed the (K!=0) pattern)
    const float* sw0 = (const float*)d_in[10];
    const float* sb0 = (const float*)d_in[11];
    const float* cw0 = (const float*)d_in[12];
    const float* cb0 = (const float*)d_in[13];
    const float* kw0 = (const float*)d_in[14];
    const float* kb0 = (const float*)d_in[15];
    const float* sw1 = (const float*)d_in[16];
    const float* sb1 = (const float*)d_in[17];
    const float* cw1 = (const float*)d_in[18];
    const float* cb1 = (const float*)d_in[19];
    const float* kw1 = (const float*)d_in[20];
    const float* kb1 = (const float*)d_in[21];
    const float* fcw = (const float*)d_in[22];
    const float* fcb = (const float*)d_in[23];

    gcn_match_kernel<<<dim3(1), dim3(256), 0, stream>>>(
        ego, cav, nw1, nb1, nw2, nb2,
        sw0, sb0, cw0, cb0, kw0, kb0,
        sw1, sb1, cw1, cb1, kw1, kb1,
        fcw, fcb, (float*)d_out);
}

// Round 6
// 131.428 us; speedup vs baseline: 1.1653x; 1.1653x over previous
//
#include <hip/hip_runtime.h>
#include <math.h>

// GCN graph-matching net. Verified reductions (R0-R5, absmax ~0):
//  - K off-diag values only used via (K != 0) -> class-match pattern; edge MLPs dead.
//  - normA @ u collapses to O(N) inclusion-exclusion; x stays rank<=7.
//  - Multiplicative sinkhorn: A = 2^(t - rowmax) once; steps u=1/(Av), v=1/(A^T u).
// R6: 4-wave kernel (256 threads), quad-parallel sinkhorn, A in registers; 60
//   half-step barriers at ~850cy period -> 39.2us kernel. BEST so far.
// R7-R11: wave-0-only sinkhorn variants (A in VGPRs / LDS-streamed / pinned /
//   unrolled) all 49-59us: compiler pins register-minimal schedule (VGPR=152);
//   single-wave LDS streaming serializes; full unroll adds 32KB icache traffic.
//   VALU-busy integral constant across all -> deltas were pure stall. Abandoned.
// R12: R6 STRUCTURE + FLAG-SYNC SINKHORN. Keep 4-wave quad-parallel half-steps
//   (A stays in registers, 16 elems/thread). Replace the 54 in-loop barriers with
//   per-wave LDS flags: producers ds_write data -> s_waitcnt lgkmcnt(0) (asm) ->
//   lane0 writes monotone iteration tag; consumers spin on the 4 tags (volatile,
//   wave-uniform) then read data (in-wave DS ordering => coherent). Tags monotone
//   across sinkhorns (base 0/10/20): no resets, no ABA; overwrite safety inductive
//   (step k+2 writes wait on step k+1 flags which postdate all step k reads).
//   Half-step ~450cy vs ~850cy barrier period.

#define SK_SCALE 28.853900817779268f   // (1/TAU = 20) * log2(e)

template<int CTRL>
__device__ __forceinline__ float dppf(float x) {
    int xi = __float_as_int(x);
    int rr = __builtin_amdgcn_update_dpp(xi, xi, CTRL, 0xF, 0xF, false);
    return __int_as_float(rr);
}
__device__ __forceinline__ float quad_sum(float v) {   // sum over lane&3 quad
    v += dppf<0xB1>(v); v += dppf<0x4E>(v); return v;
}
__device__ __forceinline__ float quad_max(float v) {
    v = fmaxf(v, dppf<0xB1>(v)); v = fmaxf(v, dppf<0x4E>(v)); return v;
}
__device__ __forceinline__ float e2f(float x) { return __builtin_amdgcn_exp2f(x); }
__device__ __forceinline__ float rcpf(float x) { return __builtin_amdgcn_rcpf(x); }
__device__ __forceinline__ float dot4(const float4 a, const float4 b) {
    return a.x*b.x + a.y*b.y + a.z*b.z + a.w*b.w;
}
__device__ __forceinline__ void fma4(float4& a, float b, const float4 c) {
    a.x += b*c.x; a.y += b*c.y; a.z += b*c.z; a.w += b*c.w;
}
__device__ __forceinline__ void add4(float4& a, const float4 c) {
    a.x += c.x; a.y += c.y; a.z += c.z; a.w += c.w;
}
__device__ __forceinline__ void ld16(const float* p, float* o) {
    #pragma unroll
    for (int t = 0; t < 4; ++t) {
        float4 v = *(const float4*)(p + 4*t);
        o[4*t+0]=v.x; o[4*t+1]=v.y; o[4*t+2]=v.z; o[4*t+3]=v.w;
    }
}
__device__ __forceinline__ float dotsum16(const float* a, const float* b) {
    float s0=0,s1=0,s2=0,s3=0;
    #pragma unroll
    for (int t = 0; t < 4; ++t) {
        s0 += a[4*t+0]*b[4*t+0]; s1 += a[4*t+1]*b[4*t+1];
        s2 += a[4*t+2]*b[4*t+2]; s3 += a[4*t+3]*b[4*t+3];
    }
    return (s0+s1)+(s2+s3);
}
__device__ __forceinline__ float sum16(const float* a) {
    float s0=0,s1=0,s2=0,s3=0;
    #pragma unroll
    for (int t = 0; t < 4; ++t) {
        s0 += a[4*t+0]; s1 += a[4*t+1]; s2 += a[4*t+2]; s3 += a[4*t+3];
    }
    return (s0+s1)+(s2+s3);
}

// Spin until all 4 per-wave tags >= tag. Wave-uniform branch (same addresses in
// all lanes). Volatile -> a fresh ds_read each pass; HW has no LDS cache.
__device__ __forceinline__ void poll4(const volatile int* f, int tag) {
    while ((f[0] < tag) | (f[1] < tag) | (f[2] < tag) | (f[3] < tag)) {}
    asm volatile("" ::: "memory");   // compiler fence: no data-load hoist above poll
}
// Producer-side fence: drain this wave's LDS writes, then publish tag (lane 0).
__device__ __forceinline__ void publish(volatile int* f, int wv, int lane, int tag) {
    asm volatile("s_waitcnt lgkmcnt(0)" ::: "memory");
    __builtin_amdgcn_sched_barrier(0);
    if (lane == 0) f[wv] = tag;
}

// Multiplicative sinkhorn, 20 steps. tq: row r, cols 16q+m (log2-domain,
// pre-scaled); tt: rows 16q+m, col r. Leaves A in aq/att, final u (it18)/v (it19).
// Sync: ONE barrier (it0 u + rm), then flag protocol for its 1..19, trailing
// barrier so callers can read up/vp. Tags: u-step i -> fU=base+i (i=1..9, its
// 2,4..18); v-step j -> fV=base+j (j=1..10, its 1,3..19). base monotone/sinkhorn.
__device__ __forceinline__ void sk_mult(const float* tq, const float* tt, int q, int r,
                                        int wv, int lane, int base,
                                        float* up, float* vp, float* rmp,
                                        volatile int* fU, volatile int* fV,
                                        float* aq, float* att, float* u_out, float* v_out) {
    float rm = tq[0];
    #pragma unroll
    for (int m = 1; m < 16; ++m) rm = fmaxf(rm, tq[m]);
    rm = quad_max(rm);
    #pragma unroll
    for (int m = 0; m < 16; ++m) aq[m] = e2f(tq[m] - rm);
    float u = rcpf(quad_sum(sum16(aq)));          // it0 (row, v=1)
    if (q == 0) { rmp[r] = rm; up[r] = u; }
    __syncthreads();                               // rm + it0 u visible
    float rmq[16]; ld16(rmp + 16*q, rmq);
    #pragma unroll
    for (int m = 0; m < 16; ++m) att[m] = e2f(tt[m] - rmq[m]);
    float v;
    {   // it1 (col): consumes it0 u (barrier-synced)
        float uq[16]; ld16(up + 16*q, uq);
        v = rcpf(quad_sum(dotsum16(att, uq)));
        if (q == 0) vp[r] = v;
        publish(fV, wv, lane, base + 1);
    }
    #pragma unroll 1
    for (int p = 1; p <= 9; ++p) {                 // its 2..19 as (row, col)
        poll4(fV, base + p);                       // v of it 2p-1 ready
        float vq[16]; ld16(vp + 16*q, vq);
        u = rcpf(quad_sum(dotsum16(aq, vq)));
        if (q == 0) up[r] = u;
        publish(fU, wv, lane, base + p);
        poll4(fU, base + p);                       // u of it 2p ready
        float uq[16]; ld16(up + 16*q, uq);
        v = rcpf(quad_sum(dotsum16(att, uq)));
        if (q == 0) vp[r] = v;
        publish(fV, wv, lane, base + p + 1);
    }
    *u_out = u; *v_out = v;
    __syncthreads();                               // callers read up/vp next
}

// normA matvec, dual vectors x dual orientations, ONE barrier. u2==nullptr -> ones.
__device__ __forceinline__ void matvec_dual(const float* u1, const float* u1t,
                                            const float* u2, const float* u2t,
                                            const float* mmq, const float* dqv,
                                            const float* mmt, const float* dqt,
                                            float* o1, float* o1t, float* o2, float* o2t,
                                            int q, int r,
                                            float* WR1, float* WC1, float* WR2, float* WC2) {
    float rs1=0, rs2=0, cs1=0, cs2=0;
    #pragma unroll
    for (int m = 0; m < 16; ++m) {
        float md = mmq[m]*dqv[m], mdt = mmt[m]*dqt[m];
        rs1 += md * u1[m];               cs1 += mdt * u1t[m];
        rs2 += md * (u2 ? u2[m] : 1.0f); cs2 += mdt * (u2t ? u2t[m] : 1.0f);
    }
    rs1 = quad_sum(rs1); rs2 = quad_sum(rs2);
    cs1 = quad_sum(cs1); cs2 = quad_sum(cs2);
    if (q == 0) { WR1[r]=rs1; WR2[r]=rs2; WC1[r]=cs1; WC2[r]=cs2; }
    __syncthreads();
    float wr1[16], wc1[16], wr2[16], wc2[16];
    ld16(WR1 + 16*q, wr1); ld16(WC1 + 16*q, wc1);
    ld16(WR2 + 16*q, wr2); ld16(WC2 + 16*q, wc2);
    float W1 = quad_sum(sum16(wc1));
    float W2 = quad_sum(sum16(wc2));
    #pragma unroll
    for (int m = 0; m < 16; ++m) {
        float d = dqv[m], mm = mmq[m];
        float u1m = u1[m], u2m = u2 ? u2[m] : 1.0f;
        float z1 = mm*d*u1m, z2 = mm*d*u2m;
        o1[m] = d*((1.0f+mm)*d*u1m + mm*(W1 - rs1 - wc1[m] + z1));
        o2[m] = d*((1.0f+mm)*d*u2m + mm*(W2 - rs2 - wc2[m] + z2));
        float dt = dqt[m], mt = mmt[m];
        float u1tm = u1t[m], u2tm = u2t ? u2t[m] : 1.0f;
        float z1t = mt*dt*u1tm, z2t = mt*dt*u2tm;
        o1t[m] = dt*((1.0f+mt)*dt*u1tm + mt*(W1 - wr1[m] - cs1 + z1t));
        o2t[m] = dt*((1.0f+mt)*dt*u2tm + mt*(W2 - wr2[m] - cs2 + z2t));
    }
}

extern "C" __global__ __launch_bounds__(256, 1)
void gcn_match_kernel(const float* ego, const float* cav,
                      const float* nw1, const float* nb1, const float* nw2, const float* nb2,
                      const float* sw0, const float* sb0, const float* cw0, const float* cb0,
                      const float* kw0, const float* kb0,
                      const float* sw1, const float* sb1, const float* cw1, const float* cb1,
                      const float* kw1, const float* kb1,
                      const float* fcw, const float* fcb,
                      float* out) {
    __shared__ __align__(16) float sh_hT1[64 * 68];   // ego h^T | later dots (natural)
    __shared__ __align__(16) float sh_hT2[64 * 68];   // cav h^T | later dots^T
    __shared__ __align__(16) float sh_w2[2048];
    __shared__ __align__(16) float sh_f1[64 * 36];
    __shared__ __align__(16) float sh_f2[64 * 36];
    __shared__ __align__(16) float sh_nw1[320];
    __shared__ __align__(16) float sh_nb1[64], sh_nb2[32];
    __shared__ __align__(16) float sh_cls1[64], sh_cf1[64], sh_cls2[64], sh_cf2[64];
    __shared__ __align__(16) float sh_n1[64], sh_n2[64], sh_Dr[64], sh_Dc[64];
    __shared__ __align__(16) float sh_up[64], sh_vp[64], sh_rmp[64];
    __shared__ __align__(16) float sh_WR1[64], sh_WC1[64], sh_WR2[64], sh_WC2[64];
    __shared__ __align__(16) float sh_sw0[16], sh_sb0[16], sh_cw0[16], sh_cb0[16];
    __shared__ __align__(16) float sh_sb1[16], sh_cb1[16];
    __shared__ __align__(16) float sh_sw1[256], sh_cw1[256];
    __shared__ __align__(16) float sh_kw0[16], sh_kw1[16], sh_fcw[16];
    __shared__ float sh_kb[4];        // kb0, kb1, fcb
    __shared__ float sh_avec[7 * 16];
    __shared__ float sh_coef[18];
    __shared__ __align__(16) int sh_fU[4], sh_fV[4];   // per-wave sinkhorn tags

    const int tid = threadIdx.x;
    const int wv = tid >> 6, lane = tid & 63;
    const int r = tid >> 2, q = tid & 3;

    // ================= P0a: stage everything (one parallel load round) ==========
    ((float4*)sh_w2)[tid]       = ((const float4*)nw2)[tid];
    ((float4*)sh_w2)[tid + 256] = ((const float4*)nw2)[tid + 256];
    if (tid < 80)       ((float4*)sh_nw1)[tid]      = ((const float4*)nw1)[tid];
    else if (tid < 96)  ((float4*)sh_nb1)[tid-80]   = ((const float4*)nb1)[tid-80];
    else if (tid < 104) ((float4*)sh_nb2)[tid-96]   = ((const float4*)nb2)[tid-96];
    else if (tid < 108) ((float4*)sh_sw0)[tid-104]  = ((const float4*)sw0)[tid-104];
    else if (tid < 112) ((float4*)sh_sb0)[tid-108]  = ((const float4*)sb0)[tid-108];
    else if (tid < 116) ((float4*)sh_cw0)[tid-112]  = ((const float4*)cw0)[tid-112];
    else if (tid < 120) ((float4*)sh_cb0)[tid-116]  = ((const float4*)cb0)[tid-116];
    else if (tid < 124) ((float4*)sh_sb1)[tid-120]  = ((const float4*)sb1)[tid-120];
    else if (tid < 128) ((float4*)sh_cb1)[tid-124]  = ((const float4*)cb1)[tid-124];
    else if (tid < 192) ((float4*)sh_sw1)[tid-128]  = ((const float4*)sw1)[tid-128];
    else                ((float4*)sh_cw1)[tid-192]  = ((const float4*)cw1)[tid-192];
    if (tid < 4)        ((float4*)sh_kw0)[tid]      = ((const float4*)kw0)[tid];
    else if (tid < 8)   ((float4*)sh_kw1)[tid-4]    = ((const float4*)kw1)[tid-4];
    else if (tid < 12)  ((float4*)sh_fcw)[tid-8]    = ((const float4*)fcw)[tid-8];
    else if (tid == 12) sh_kb[0] = kb0[0];
    else if (tid == 13) sh_kb[1] = kb1[0];
    else if (tid == 14) sh_kb[2] = fcb[0];
    else if (tid == 15) {
        sh_fU[0]=0; sh_fU[1]=0; sh_fU[2]=0; sh_fU[3]=0;
        sh_fV[0]=0; sh_fV[1]=0; sh_fV[2]=0; sh_fV[3]=0;
    }
    if (tid < 64) { sh_cls1[tid] = ego[tid*8+6]; sh_cf1[tid] = ego[tid*8+7]; }
    else if (tid < 128) { int j = tid-64; sh_cls2[j] = cav[j*8+6]; sh_cf2[j] = cav[j*8+7]; }
    __syncthreads();

    // ================= P0b: hidden MLP (transposed store), 4 waves ==============
    {
        float4 ea = ((const float4*)ego)[lane*2], eb = ((const float4*)ego)[lane*2+1];
        float4 ca = ((const float4*)cav)[lane*2], cb = ((const float4*)cav)[lane*2+1];
        #pragma unroll
        for (int kk = 0; kk < 16; ++kk) {
            int k = 16*wv + kk;
            float b1 = sh_nb1[k];
            float w0 = sh_nw1[k],       w1 = sh_nw1[64+k],  w2_ = sh_nw1[128+k];
            float w3 = sh_nw1[192+k],   w4 = sh_nw1[256+k];
            sh_hT1[k*68 + lane] = fmaxf(b1 + ea.y*w0 + ea.z*w1 + ea.w*w2_ + eb.x*w3 + eb.y*w4, 0.0f);
            sh_hT2[k*68 + lane] = fmaxf(b1 + ca.y*w0 + ca.z*w1 + ca.w*w2_ + cb.x*w3 + cb.y*w4, 0.0f);
        }
    }
    __syncthreads();

    // ================= P1: GEMMs (waves 0,1) + avec/coef (wave 2) ===============
    if (wv < 2) {
        const float* HT = (wv == 0) ? sh_hT1 : sh_hT2;
        float* F  = (wv == 0) ? sh_f1 : sh_f2;
        float* NN = (wv == 0) ? sh_n1 : sh_n2;
        const int rr = lane >> 2, oq = lane & 3;
        float4 accA[4], accB[4];
        #pragma unroll
        for (int m = 0; m < 4; ++m) { accA[m] = make_float4(0,0,0,0); accB[m] = accA[m]; }
        #pragma unroll 4
        for (int k = 0; k < 64; ++k) {
            float4 hq = *(const float4*)(HT + k*68 + 4*rr);
            float4 wA = *(const float4*)(sh_w2 + k*32 + 4*oq);
            float4 wB = *(const float4*)(sh_w2 + k*32 + 16 + 4*oq);
            fma4(accA[0], hq.x, wA); fma4(accB[0], hq.x, wB);
            fma4(accA[1], hq.y, wA); fma4(accB[1], hq.y, wB);
            fma4(accA[2], hq.z, wA); fma4(accB[2], hq.z, wB);
            fma4(accA[3], hq.w, wA); fma4(accB[3], hq.w, wB);
        }
        float4 b2a = *(const float4*)(sh_nb2 + 4*oq);
        float4 b2b = *(const float4*)(sh_nb2 + 16 + 4*oq);
        float sq[4];
        #pragma unroll
        for (int m = 0; m < 4; ++m) {
            add4(accA[m], b2a); add4(accB[m], b2b);
            int row = 4*rr + m;
            *(float4*)(F + row*36 + 4*oq)      = accA[m];
            *(float4*)(F + row*36 + 16 + 4*oq) = accB[m];
            float q2 = dot4(accA[m], accA[m]) + dot4(accB[m], accB[m]);
            q2 += dppf<0xB1>(q2); q2 += dppf<0x4E>(q2);
            sq[m] = q2;
        }
        if (oq == 0) {
            #pragma unroll
            for (int m = 0; m < 4; ++m)
                NN[4*rr + m] = fmaxf(sqrtf(sq[m]), 1e-8f);
        }
    } else if (wv == 2) {
        if (lane < 16) {   // avec from LDS-staged weights
            int o = lane;
            float ax=0, av=0, as_=0, aw=0, au=0, ae=0, a1=0;
            #pragma unroll
            for (int k = 0; k < 16; ++k) {
                float s0k = sh_sw0[k], c0k = sh_cw0[k], b0k = sh_sb0[k] + sh_cb0[k];
                float s1ko = sh_sw1[k*16+o], c1ko = sh_cw1[k*16+o];
                ax += s0k*s1ko;  av += c0k*s1ko + s0k*c1ko;  as_ += s1ko;
                aw += c0k*c1ko;  au += c1ko;  ae += b0k*c1ko;  a1 += b0k*s1ko;
            }
            a1 += sh_sb1[o] + sh_cb1[o];
            sh_avec[0*16+o]=ax; sh_avec[1*16+o]=av; sh_avec[2*16+o]=as_;
            sh_avec[3*16+o]=aw; sh_avec[4*16+o]=au; sh_avec[5*16+o]=ae;
            sh_avec[6*16+o]=a1;
        }
        if (lane < 18) {   // coef (same wave: avec writes visible via lgkmcnt)
            int t = lane; float c = 0.0f;
            if (t == 0)      { for (int k = 0; k < 16; ++k) c += sh_sw0[k]*sh_kw0[k]; }
            else if (t == 1) { for (int k = 0; k < 16; ++k) c += sh_cw0[k]*sh_kw0[k]; }
            else if (t == 2) { for (int k = 0; k < 16; ++k) c += (sh_sb0[k]+sh_cb0[k])*sh_kw0[k]; c += sh_kb[0]; }
            else if (t < 10) { int v = t-3;
                for (int o = 0; o < 16; ++o) c += sh_avec[v*16+o]*sh_kw1[o];
                if (v == 6) c += sh_kb[1];
            } else if (t < 17) { int v = t-10;
                for (int o = 0; o < 16; ++o) c += sh_avec[v*16+o]*sh_fcw[o];
                if (v == 6) c += sh_kb[2];
            } else { for (int o = 0; o < 16; ++o) c += sh_fcw[o]; }
            sh_coef[t] = c;
        }
    }
    __syncthreads();

    // ================= P2: dots (all 4 waves, natural + transposed) + mm/degrees =
    {
        const int sc = lane & 15, rc = lane >> 4;
        float dt[4][4];
        #pragma unroll
        for (int m = 0; m < 4; ++m)
            #pragma unroll
            for (int k = 0; k < 4; ++k) dt[m][k] = 0.0f;
        for (int kq = 0; kq < 8; ++kq) {
            float4 f2q[4];
            #pragma unroll
            for (int k = 0; k < 4; ++k)
                f2q[k] = *(const float4*)(sh_f2 + (sc + 16*k)*36 + 4*kq);
            #pragma unroll
            for (int m = 0; m < 4; ++m) {
                int rrow = 16*m + 4*wv + rc;
                float4 f1q = *(const float4*)(sh_f1 + rrow*36 + 4*kq);
                #pragma unroll
                for (int k = 0; k < 4; ++k) dt[m][k] += dot4(f1q, f2q[k]);
            }
        }
        #pragma unroll
        for (int m = 0; m < 4; ++m) {
            int rrow = 16*m + 4*wv + rc;
            #pragma unroll
            for (int k = 0; k < 4; ++k) {
                sh_hT1[rrow*68 + sc + 16*k] = dt[m][k];       // dots natural
                sh_hT2[(sc + 16*k)*68 + rrow] = dt[m][k];     // dots transposed
            }
        }
    }
    float mmq[16], mmt[16], cfq[16], cft[16];
    float Drr, Dcr;
    {
        float c2q[16], c1q[16], f2v[16], f1v[16];
        ld16(sh_cls2 + 16*q, c2q); ld16(sh_cls1 + 16*q, c1q);
        ld16(sh_cf2 + 16*q, f2v);  ld16(sh_cf1 + 16*q, f1v);
        const float cls1r = sh_cls1[r], cls2r = sh_cls2[r];
        const float cf1r = sh_cf1[r],  cf2r  = sh_cf2[r];
        float dr = 0, dc = 0;
        #pragma unroll
        for (int m = 0; m < 16; ++m) {
            mmq[m] = (cls1r == c2q[m]) ? 1.0f : 0.0f;
            mmt[m] = (c1q[m] == cls2r) ? 1.0f : 0.0f;
            dr += mmq[m]; dc += mmt[m];
            cfq[m] = sqrtf(cf1r * f2v[m]);
            cft[m] = sqrtf(f1v[m] * cf2r);
        }
        Drr = quad_sum(dr);
        Dcr = quad_sum(dc);
        if (q == 0) { sh_Dr[r] = Drr; sh_Dc[r] = Dcr; }
    }
    __syncthreads();

    // ================= P3: dinv + x0, both orientations ==========================
    float dqv[16], dqt[16], x0[16], x0t[16];
    {
        float dcq[16], drq[16], n2q[16], n1q[16], dotq[16], dotTq[16];
        ld16(sh_Dc + 16*q, dcq); ld16(sh_Dr + 16*q, drq);
        ld16(sh_n2 + 16*q, n2q); ld16(sh_n1 + 16*q, n1q);
        ld16(sh_hT1 + r*68 + 16*q, dotq);
        ld16(sh_hT2 + r*68 + 16*q, dotTq);
        float Tdeg = quad_sum(sum16(dcq));
        const float n1r = sh_n1[r], n2r = sh_n2[r];
        #pragma unroll
        for (int m = 0; m < 16; ++m) {
            dqv[m] = (mmq[m] != 0.0f) ? (1.0f / sqrtf(Tdeg - Drr - dcq[m] + 3.0f)) : 1.0f;
            dqt[m] = (mmt[m] != 0.0f) ? (1.0f / sqrtf(Tdeg - drq[m] - Dcr + 3.0f)) : 1.0f;
            x0[m]  = mmq[m] * cfq[m] * (dotq[m]  / (n1r * n2q[m]));
            x0t[m] = mmt[m] * cft[m] * (dotTq[m] / (n1q[m] * n2r));
        }
    }

    // ================= matvec A: v0 = normA x0, oe = normA 1 =====================
    float v0[16], v0t[16], oe[16], oet[16];
    matvec_dual(x0, x0t, nullptr, nullptr, mmq, dqv, mmt, dqt,
                v0, v0t, oe, oet, q, r, sh_WR1, sh_WC1, sh_WR2, sh_WC2);

    // ================= t0 + fold x0/oe into t1/sacc bases ========================
    float t0q[16], t0t[16], t1b[16], t1bt[16], sbse[16], sbst[16];
    {
        float c0 = sh_coef[0], c1 = sh_coef[1], c2 = sh_coef[2];
        float ctx = sh_coef[3], ctv = sh_coef[4];
        float ce_ = sh_coef[8], ct1 = sh_coef[9];
        float csx = sh_coef[10], csv = sh_coef[11];
        float ce2 = sh_coef[15], cs1 = sh_coef[16];
        #pragma unroll
        for (int m = 0; m < 16; ++m) {
            t0q[m] = (c0*x0[m]  + c1*v0[m]  + c2) * SK_SCALE;
            t0t[m] = (c0*x0t[m] + c1*v0t[m] + c2) * SK_SCALE;
            t1b[m]  = ctx*x0[m]  + ctv*v0[m]  + ct1 + ce_*oe[m];
            t1bt[m] = ctx*x0t[m] + ctv*v0t[m] + ct1 + ce_*oet[m];
            sbse[m] = csx*x0[m]  + csv*v0[m]  + cs1 + ce2*oe[m];
            sbst[m] = csx*x0t[m] + csv*v0t[m] + cs1 + ce2*oet[m];
        }
    }

    // ================= sinkhorn0 -> s0 (flag-synced, base 0) =====================
    float aq[16], att[16], u_, v_;
    sk_mult(t0q, t0t, q, r, wv, lane, 0, sh_up, sh_vp, sh_rmp, sh_fU, sh_fV,
            aq, att, &u_, &v_);
    float s0v[16], s0t[16];
    {
        float vq[16], uq[16];
        ld16(sh_vp + 16*q, vq); ld16(sh_up + 16*q, uq);
        #pragma unroll
        for (int m = 0; m < 16; ++m) {
            s0v[m] = aq[m] * u_ * vq[m];
            s0t[m] = att[m] * uq[m] * v_;
        }
    }

    // ================= matvec B (v0, s0) -> t1, sacc =============================
    float ov[16], ovt[16], os[16], ost[16];
    matvec_dual(v0, v0t, s0v, s0t, mmq, dqv, mmt, dqt,
                ov, ovt, os, ost, q, r, sh_WR1, sh_WC1, sh_WR2, sh_WC2);
    float t1q[16], t1t[16], sacc[16], sacct[16];
    {
        float cts = sh_coef[5], cw_ = sh_coef[6], cu_ = sh_coef[7];
        float css = sh_coef[12], cw2 = sh_coef[13], cu2 = sh_coef[14];
        #pragma unroll
        for (int m = 0; m < 16; ++m) {
            t1q[m] = (t1b[m]  + cts*s0v[m] + cw_*ov[m]  + cu_*os[m])  * SK_SCALE;
            t1t[m] = (t1bt[m] + cts*s0t[m] + cw_*ovt[m] + cu_*ost[m]) * SK_SCALE;
            sacc[m]  = sbse[m] + css*s0v[m] + cw2*ov[m]  + cu2*os[m];
            sacct[m] = sbst[m] + css*s0t[m] + cw2*ovt[m] + cu2*ost[m];
        }
    }

    // ================= sinkhorn1 -> sacc += c17*s1 (base 10) =====================
    sk_mult(t1q, t1t, q, r, wv, lane, 10, sh_up, sh_vp, sh_rmp, sh_fU, sh_fV,
            aq, att, &u_, &v_);
    {
        float c17 = sh_coef[17];
        float vq[16], uq[16];
        ld16(sh_vp + 16*q, vq); ld16(sh_up + 16*q, uq);
        #pragma unroll
        for (int m = 0; m < 16; ++m) {
            sacc[m]  += c17 * aq[m] * u_ * vq[m];
            sacct[m] += c17 * att[m] * uq[m] * v_;
        }
    }
    __syncthreads();   // protect up/vp reads before sinkhorn2 overwrites

    // ================= sinkhorn2 on s = sacc^T -> output (base 20) ===============
    {
        float t2q[16], t2t[16];
        #pragma unroll
        for (int m = 0; m < 16; ++m) {
            t2q[m] = sacct[m] * SK_SCALE;   // s[r][16q+m] = Sc(16q+m, r)
            t2t[m] = sacc[m] * SK_SCALE;
        }
        sk_mult(t2q, t2t, q, r, wv, lane, 20, sh_up, sh_vp, sh_rmp, sh_fU, sh_fV,
                aq, att, &u_, &v_);
        float vq[16]; ld16(sh_vp + 16*q, vq);
        #pragma unroll
        for (int t = 0; t < 4; ++t) {
            float4 o4;
            o4.x = aq[4*t+0] * u_ * vq[4*t+0];
            o4.y = aq[4*t+1] * u_ * vq[4*t+1];
            o4.z = aq[4*t+2] * u_ * vq[4*t+2];
            o4.w = aq[4*t+3] * u_ * vq[4*t+3];
            *(float4*)(out + r*64 + 16*q + 4*t) = o4;
        }
    }
}

extern "C" void kernel_launch(void* const* d_in, const int* in_sizes, int n_in,
                              void* d_out, int out_size, void* d_ws, size_t ws_size,
                              hipStream_t stream) {
    const float* ego = (const float*)d_in[0];
    const float* cav = (const float*)d_in[1];
    const float* nw1 = (const float*)d_in[2];
    const float* nb1 = (const float*)d_in[3];
    const float* nw2 = (const float*)d_in[4];
    const float* nb2 = (const float*)d_in[5];
    // d_in[6..9] = edge MLP weights: dead code (edge values only feed the (K!=0) pattern)
    const float* sw0 = (const float*)d_in[10];
    const float* sb0 = (const float*)d_in[11];
    const float* cw0 = (const float*)d_in[12];
    const float* cb0 = (const float*)d_in[13];
    const float* kw0 = (const float*)d_in[14];
    const float* kb0 = (const float*)d_in[15];
    const float* sw1 = (const float*)d_in[16];
    const float* sb1 = (const float*)d_in[17];
    const float* cw1 = (const float*)d_in[18];
    const float* cb1 = (const float*)d_in[19];
    const float* kw1 = (const float*)d_in[20];
    const float* kb1 = (const float*)d_in[21];
    const float* fcw = (const float*)d_in[22];
    const float* fcb = (const float*)d_in[23];

    gcn_match_kernel<<<dim3(1), dim3(256), 0, stream>>>(
        ego, cav, nw1, nb1, nw2, nb2,
        sw0, sb0, cw0, cb0, kw0, kb0,
        sw1, sb1, cw1, cb1, kw1, kb1,
        fcw, fcb, (float*)d_out);
}